// Round 19
// baseline (4956.359 us; speedup 1.0000x reference)
//
#include <hip/hip_runtime.h>
#include <hip/hip_bf16.h>
#include <math.h>

#define BATCH 4096
#define HID   512
#define NACT  18
#define DIM   1043
#define MEMN  32768
#define TOPK  32
#define G4H   2048
#define NCHUNK 16
#define CHUNKM (MEMN / NCHUNK)   /* 2048 */
#define KCP   512   /* gates-GEMM panel size — DO NOT CHANGE: verified numerics */

// ---- workspace layout (f32-element offsets). PEAK = 9437184 f32 = 36.0 MiB
#define OFF_C1   0ull        // f32 [4096,512]
#define OFF_Q    2097152ull  // f32 [4096,512]
#define OFF_H1B  4194304ull  // bf16 [4096,512]
#define OFF_PV   5242880ull  // f32 [4096,16,32]
#define OFF_PI   7340032ull  // i32 [4096,16,32]
#define OFF_MEMB 5242880ull  // bf16 [4096,1043] ALIASES pv/pi

// ---- output offsets (FLOAT32 elements), return order:
// critic[B,1], actor[B,18], h2[B,512], c2[B,512], inds[B,32], weights[B,32]
#define OUT_CRITIC 0
#define OUT_ACTOR  4096
#define OUT_H2     77824
#define OUT_C2     2174976
#define OUT_INDS   4272128
#define OUT_W      4403200

__device__ __forceinline__ float toF_(float x) { return x; }
__device__ __forceinline__ float toF_(__hip_bfloat16 x) { return __bfloat162float(x); }
__device__ __forceinline__ float sigf_(float x) { return 1.0f / (1.0f + expf(-x)); }

// numpy SIMD f32 exp emulation; sigmoid = 1/(1+exp(-x)) single-rounded.
// tanh: correctly rounded via f64.  DO NOT CHANGE: verified numerics.
__device__ __forceinline__ float np_expf(float x) {
  const float magic = 12582912.0f;  // 0x1.8p23
  float q = fmaf(x, 1.442695040888963f, magic) - magic;  // rint(x*log2e)
  float r = fmaf(q, -6.93145752e-1f, x);
  r = fmaf(q, -1.42860677e-6f, r);
  float num = fmaf(5.082762527590693718096e-04f, r, 6.757896990527504603057e-03f);
  num = fmaf(num, r, 5.114512081637298353406e-02f);
  num = fmaf(num, r, 2.473615434895520810817e-01f);
  num = fmaf(num, r, 7.257664613233124478488e-01f);
  num = fmaf(num, r, 9.999999999980870924916e-01f);
  float den = fmaf(2.159509375685829852307e-02f, r, -2.742335390411667452936e-01f);
  den = fmaf(den, r, 1.0f);
  float poly = __fdiv_rn(num, den);
  int qi = (int)q;
  float scale = __uint_as_float((unsigned)(127 + qi) << 23);
  return __fmul_rn(poly, scale);
}
__device__ __forceinline__ float np_sigmoidf(float x) {
  const float e = np_expf(-x);
  return __fdiv_rn(1.0f, __fadd_rn(1.0f, e));
}
__device__ __forceinline__ float cr_tanhf(float x) { return (float)tanh((double)x); }

// ============================================================================
// Fused GEMM + LSTM cell — VERIFIED NUMERICS (R16/R17 pass). Unchanged.
// ============================================================================
template<int PASS, typename TA, typename TC>
__global__ __launch_bounds__(512, 2) void gemm_lstm(
    const TA* __restrict__ A1, const TA* __restrict__ A2,
    const float* __restrict__ W1, const float* __restrict__ W2,
    const float* __restrict__ bias, const TC* __restrict__ cprev,
    float* __restrict__ c1out, __hip_bfloat16* __restrict__ h1b,
    float* __restrict__ outH2, float* __restrict__ outC2)
{
  __shared__ float as[32][66];
  __shared__ float bs[32][132];
  const int tid = threadIdx.x;
  const int b0 = blockIdx.y * 64;
  const int h0 = blockIdx.x * 32;
  const int tr = tid >> 5, tc = tid & 31;
  float accA[4][4] = {};
  float accB[4][4] = {};

  auto run = [&](const TA* __restrict__ A, const float* __restrict__ W,
                 int Ksz, float (&acc)[4][4]) {
    float accP[4][4] = {};
    for (int k0 = 0; k0 < Ksz; k0 += 32) {
      {
        const int r = tid >> 3, kq = tid & 7;
        #pragma unroll
        for (int j = 0; j < 4; ++j) {
          const int kidx = k0 + 4 * kq + j;
          as[4 * kq + j][r] =
              (kidx < Ksz) ? toF_(A[(size_t)(b0 + r) * Ksz + kidx]) : 0.0f;
        }
      }
      {
        const int kk = tid >> 4, sub = tid & 15;
        const bool ok = (k0 + kk) < Ksz;
        #pragma unroll
        for (int g = 0; g < 4; ++g)
          #pragma unroll
          for (int r2 = 0; r2 < 2; ++r2) {
            const float w =
                ok ? W[(size_t)(k0 + kk) * G4H + 512 * g + h0 + 2 * sub + r2] : 0.0f;
            bs[kk][(2 * sub + r2) * 4 + g] = w;
          }
      }
      __syncthreads();
      #pragma unroll
      for (int kk = 0; kk < 32; ++kk) {
        float a[4], b[4];
        #pragma unroll
        for (int u = 0; u < 4; ++u) a[u] = as[kk][4 * tr + u];
        #pragma unroll
        for (int u = 0; u < 4; ++u) b[u] = bs[kk][4 * tc + u];
        #pragma unroll
        for (int jj = 0; jj < 4; ++jj)
          #pragma unroll
          for (int g = 0; g < 4; ++g)
            accP[jj][g] = fmaf(a[jj], b[g], accP[jj][g]);
      }
      __syncthreads();
      if (((k0 + 32) % KCP == 0) || (k0 + 32 >= Ksz)) {
        #pragma unroll
        for (int jj = 0; jj < 4; ++jj)
          #pragma unroll
          for (int g = 0; g < 4; ++g) {
            acc[jj][g] = __fadd_rn(acc[jj][g], accP[jj][g]);
            accP[jj][g] = 0.0f;
          }
      }
    }
  };
  run(A1, W1, DIM, accA);   // K=1043: panels 512 | 512 | 19
  run(A2, W2, HID, accB);   // K=512: single chain

  const int h = h0 + tc;
  const float bf = bias[h];
  const float bi = bias[512 + h];
  const float bo = bias[1024 + h];
  const float bg = bias[1536 + h];
  #pragma unroll
  for (int jj = 0; jj < 4; ++jj) {
    const int b = b0 + 4 * tr + jj;
    const float fv = __fadd_rn(__fadd_rn(accA[jj][0], accB[jj][0]), bf);
    const float iv = __fadd_rn(__fadd_rn(accA[jj][1], accB[jj][1]), bi);
    const float ov = __fadd_rn(__fadd_rn(accA[jj][2], accB[jj][2]), bo);
    const float gv = __fadd_rn(__fadd_rn(accA[jj][3], accB[jj][3]), bg);
    const float cp = toF_(cprev[(size_t)b * HID + h]);
    if constexpr (PASS == 1) {
      const float sf = np_sigmoidf(fv);
      const float si = np_sigmoidf(iv);
      const float so = np_sigmoidf(ov);
      const float tg = cr_tanhf(gv);
      const float cn = __fadd_rn(__fmul_rn(sf, cp), __fmul_rn(si, tg));
      const float hn = __fmul_rn(so, cr_tanhf(cn));
      c1out[(size_t)b * HID + h] = cn;
      h1b[(size_t)b * HID + h] = __float2bfloat16(hn);
    } else {
      const float cn = sigf_(fv) * cp + sigf_(iv) * tanhf(gv);
      const float hn = sigf_(ov) * tanhf(cn);
      outC2[(size_t)b * HID + h] = cn;
      outH2[(size_t)b * HID + h] = hn;
    }
  }
}

// ============================================================================
// LayerNorm(c1) -> q (numpy pairwise emulation — verified). Unchanged.
// ============================================================================
__global__ __launch_bounds__(256) void ln_q_np(
    const float* __restrict__ c1, const float* __restrict__ ln_g,
    const float* __restrict__ ln_b, float* __restrict__ q)
{
  const int tid = threadIdx.x, lane = tid & 63;
  const int r = blockIdx.x * 4 + (tid >> 6);
  const float* c = c1 + (size_t)r * HID;

  float part;
  {
    const int bi = (lane & 31) >> 3, j = lane & 7;
    const float* p = c + bi * 128 + j;
    float s = p[0];
    #pragma unroll
    for (int k = 1; k < 16; ++k) s = __fadd_rn(s, p[8 * k]);
    part = s;
  }
  part = __fadd_rn(part, __shfl_xor(part, 1, 32));
  part = __fadd_rn(part, __shfl_xor(part, 2, 32));
  part = __fadd_rn(part, __shfl_xor(part, 4, 32));
  part = __fadd_rn(part, __shfl_xor(part, 8, 32));
  part = __fadd_rn(part, __shfl_xor(part, 16, 32));
  const float mean = __fmul_rn(part, 1.0f / 512.0f);

  float part2;
  {
    const int bi = (lane & 31) >> 3, j = lane & 7;
    const float* p = c + bi * 128 + j;
    float d = __fsub_rn(p[0], mean);
    float s = __fmul_rn(d, d);
    #pragma unroll
    for (int k = 1; k < 16; ++k) {
      d = __fsub_rn(p[8 * k], mean);
      s = __fadd_rn(s, __fmul_rn(d, d));
    }
    part2 = s;
  }
  part2 = __fadd_rn(part2, __shfl_xor(part2, 1, 32));
  part2 = __fadd_rn(part2, __shfl_xor(part2, 2, 32));
  part2 = __fadd_rn(part2, __shfl_xor(part2, 4, 32));
  part2 = __fadd_rn(part2, __shfl_xor(part2, 8, 32));
  part2 = __fadd_rn(part2, __shfl_xor(part2, 16, 32));
  const float var = __fmul_rn(part2, 1.0f / 512.0f);

  const float S = __fsqrt_rn(__fadd_rn(var, 1e-5f));
  #pragma unroll
  for (int u = 0; u < 8; ++u) {
    const int i = lane + 64 * u;
    const float dv = __fsub_rn(c[i], mean);
    q[(size_t)r * HID + i] =
        __fadd_rn(__fmul_rn(__fdiv_rn(dv, S), ln_g[i]), ln_b[i]);
  }
}

// ============================================================================
// Fused scores GEMM + exact top-32 — 128x256 tile, 8x8 register block.
// R18 RETILE with the SPILL FIXED: __launch_bounds__(512, 2) -> 128-VGPR cap
// (R18's (512,4) forced 64 VGPR -> acc[64] spilled to scratch: 593MB writes).
// 2 blocks/CU (LDS 53.8KB x2 = 107.5KB). Numerics bit-identical (single
// ascending-K fmaf chain per output; verified merge idiom).
// ============================================================================
__global__ __launch_bounds__(512, 2) void score_topk(
    const float* __restrict__ Q, const float* __restrict__ Km,
    float* __restrict__ pv, int* __restrict__ pi)
{
  __shared__ float as[32][132];   // [k][row 0..127] (+pad)
  __shared__ float bs[32][288];   // [k][off(col)], off = col + 4*(col>>5)
  const int tid = threadIdx.x;
  const int lane = tid & 63;
  const int w = tid >> 6;
  const int cg = lane & 31;
  const int hi = lane >> 5;
  const int b0 = blockIdx.y * 128;
  const int chunkBase = blockIdx.x * CHUNKM;
  const int rowbase = 16 * w + 8 * hi;          // tile-row base (8 rows/thread)
  const int boff = 8 * cg + 4 * (cg >> 2);      // swizzled b-read base (16B-aligned)

  // staging maps
  const int ar = tid & 127;        // A row
  const int akq = tid >> 7;        // A k-octet (k = 8*akq + j)
  const int bcol = tid >> 1;       // B col 0..255
  const int bkq = tid & 1;         // B k-half (k = 16*bkq + j)
  const int bwo = bcol + 4 * (bcol >> 5);  // swizzled write base

  float listV[8];
  int   listI[8];
  #pragma unroll
  for (int j = 0; j < 8; ++j) { listV[j] = -INFINITY; listI[j] = 0; }

  for (int t = 0; t < CHUNKM / 256; ++t) {
    const int m0 = chunkBase + t * 256;
    float acc[8][8] = {};
    for (int k0 = 0; k0 < HID; k0 += 32) {
      {
        const float* qp = Q + (size_t)(b0 + ar) * HID + k0 + 8 * akq;
        const float4 v0 = *(const float4*)qp;
        const float4 v1 = *(const float4*)(qp + 4);
        as[8 * akq + 0][ar] = v0.x; as[8 * akq + 1][ar] = v0.y;
        as[8 * akq + 2][ar] = v0.z; as[8 * akq + 3][ar] = v0.w;
        as[8 * akq + 4][ar] = v1.x; as[8 * akq + 5][ar] = v1.y;
        as[8 * akq + 6][ar] = v1.z; as[8 * akq + 7][ar] = v1.w;
      }
      {
        const float* kp = Km + (size_t)(m0 + bcol) * HID + k0 + 16 * bkq;
        #pragma unroll
        for (int u = 0; u < 4; ++u) {
          const float4 v = *(const float4*)(kp + 4 * u);
          bs[16 * bkq + 4 * u + 0][bwo] = v.x;
          bs[16 * bkq + 4 * u + 1][bwo] = v.y;
          bs[16 * bkq + 4 * u + 2][bwo] = v.z;
          bs[16 * bkq + 4 * u + 3][bwo] = v.w;
        }
      }
      __syncthreads();
      #pragma unroll
      for (int kk = 0; kk < 32; ++kk) {
        const float4 a0 = *(const float4*)&as[kk][rowbase];
        const float4 a1 = *(const float4*)&as[kk][rowbase + 4];
        const float4 bv0 = *(const float4*)&bs[kk][boff];
        const float4 bv1 = *(const float4*)&bs[kk][boff + 4];
        const float a[8] = {a0.x, a0.y, a0.z, a0.w, a1.x, a1.y, a1.z, a1.w};
        const float b[8] = {bv0.x, bv0.y, bv0.z, bv0.w, bv1.x, bv1.y, bv1.z, bv1.w};
        #pragma unroll
        for (int j = 0; j < 8; ++j)
          #pragma unroll
          for (int c = 0; c < 8; ++c)
            acc[j][c] = fmaf(a[j], b[c], acc[j][c]);
      }
      __syncthreads();
    }
    // ---- merge tile into running top-32 (ascending column order per half)
    #pragma unroll
    for (int j = 0; j < 8; ++j) {
      float thr = __shfl(listV[j], hi ? 63 : 31);
      while (true) {
        bool any = false;
        #pragma unroll
        for (int c = 0; c < 8; ++c) any = any || (acc[j][c] > thr);
        unsigned long long m = __ballot(any);
        if (!m) break;
        const int src = __builtin_ctzll(m);
        const bool participate = (hi == (src >> 5));
        #pragma unroll
        for (int c = 0; c < 8; ++c) {
          const float cv = __shfl(acc[j][c], src);
          const float thr_src = __shfl(thr, src);
          if (cv > thr_src) {
            const int ci = m0 + 8 * (src & 31) + c;
            const unsigned long long em = __ballot(participate && (listV[j] < cv));
            if (em) {
              const int pslot = __builtin_ctzll(em) & 31;
              const float shV = __shfl_up(listV[j], 1);
              const int  shI = __shfl_up(listI[j], 1);
              const int slot = lane & 31;
              if (participate && slot >= pslot) {
                listV[j] = (slot == pslot) ? cv : shV;
                listI[j] = (slot == pslot) ? ci : shI;
              }
              thr = __shfl(listV[j], hi ? 63 : 31);
            }
          }
        }
        if (lane == src) {
          #pragma unroll
          for (int c = 0; c < 8; ++c) acc[j][c] = -INFINITY;
        }
      }
    }
  }
  #pragma unroll
  for (int j = 0; j < 8; ++j) {
    const int row = b0 + rowbase + j;
    const size_t o = ((size_t)row * NCHUNK + blockIdx.x) * TOPK + cg;
    pv[o] = listV[j];
    pi[o] = listI[j];
  }
}

// ============================================================================
// Merge NCHUNK partial top-32s per row -> final sorted top-32 + softmax.
// Unchanged (verified).
// ============================================================================
__global__ __launch_bounds__(256) void merge_topk(
    const float* __restrict__ pv, const int* __restrict__ pi,
    float* __restrict__ outI, float* __restrict__ outW)
{
  const int tid = threadIdx.x;
  const int lane = tid & 63;
  const int b = blockIdx.x * 4 + (tid >> 6);
  float lv = -INFINITY;
  int li = 0;
  const size_t base = (size_t)b * (NCHUNK * TOPK);
  #pragma unroll
  for (int t = 0; t < (NCHUNK * TOPK) / 64; ++t) {
    const float v = pv[base + t * 64 + lane];
    const int ii = pi[base + t * 64 + lane];
    float thr = __shfl(lv, 31);
    unsigned long long m = __ballot(v > thr);
    while (m) {
      const int src = __builtin_ctzll(m);
      m &= (m - 1);
      const float cv = __shfl(v, src);
      const int ci = __shfl(ii, src);
      if (cv > thr) {
        const unsigned long long em = __ballot((lane < 32) && (lv < cv));
        if (em) {
          const int p = __builtin_ctzll(em);
          const float shV = __shfl_up(lv, 1);
          const int shI = __shfl_up(li, 1);
          if ((lane < 32) && lane >= p) {
            lv = (lane == p) ? cv : shV;
            li = (lane == p) ? ci : shI;
          }
          thr = __shfl(lv, 31);
        }
      }
    }
  }
  const float maxv = __shfl(lv, 0);
  float e = (lane < 32) ? expf(lv - maxv) : 0.0f;
  float s = e;
  #pragma unroll
  for (int d = 1; d < 64; d <<= 1) s += __shfl_xor(s, d);
  const float w = e / s;
  if (lane < 32) {
    outI[(size_t)b * TOPK + lane] = (float)li;
    outW[(size_t)b * TOPK + lane] = w;
  }
}

// ============================================================================
// memories[b,:] = sum_s w[s] * mem_values[idx[s], :]  (bf16). Unchanged.
// ============================================================================
__global__ __launch_bounds__(256) void gather_mem(
    const float* __restrict__ wf, const float* __restrict__ inf_,
    const float* __restrict__ mv, __hip_bfloat16* __restrict__ memB)
{
  __shared__ float wl[TOPK];
  __shared__ int il[TOPK];
  const int b = blockIdx.x, tid = threadIdx.x;
  if (tid < TOPK) {
    wl[tid] = wf[(size_t)b * TOPK + tid];
    il[tid] = (int)inf_[(size_t)b * TOPK + tid];
  }
  __syncthreads();
  for (int c = tid; c < DIM; c += 256) {
    float acc = 0.0f;
    #pragma unroll
    for (int s = 0; s < TOPK; ++s)
      acc = fmaf(wl[s], mv[(size_t)il[s] * DIM + c], acc);
    memB[(size_t)b * DIM + c] = __float2bfloat16(acc);
  }
}

// ============================================================================
// critic/actor heads; reads h2 (f32) from d_out, writes f32. Unchanged.
// ============================================================================
__global__ __launch_bounds__(256) void heads(
    const float* __restrict__ h2f,
    const float* __restrict__ Wc, const float* __restrict__ bc,
    const float* __restrict__ Wa, const float* __restrict__ ba,
    float* __restrict__ outC, float* __restrict__ outA)
{
  __shared__ float W[HID * 19];
  const int tid = threadIdx.x, lane = tid & 63, wid = tid >> 6;
  for (int idx = tid; idx < HID * 19; idx += 256) {
    const int l = idx / 19, o = idx % 19;
    W[idx] = (o < NACT) ? Wa[l * NACT + o] : Wc[l];
  }
  __syncthreads();
  const int r0 = blockIdx.x * 16 + wid * 4;
  for (int rr = 0; rr < 4; ++rr) {
    const int r = r0 + rr;
    float hv[8];
    #pragma unroll
    for (int u = 0; u < 8; ++u) hv[u] = h2f[(size_t)r * HID + lane + 64 * u];
    for (int o = 0; o < 19; ++o) {
      float s = 0.f;
      #pragma unroll
      for (int u = 0; u < 8; ++u) s = fmaf(hv[u], W[(lane + 64 * u) * 19 + o], s);
      #pragma unroll
      for (int d = 1; d < 64; d <<= 1) s += __shfl_xor(s, d);
      if (lane == 0) {
        if (o < NACT) outA[(size_t)r * NACT + o] = s + ba[o];
        else          outC[r] = s + bc[0];
      }
    }
  }
}

// ============================================================================
extern "C" void kernel_launch(void* const* d_in, const int* in_sizes, int n_in,
                              void* d_out, int out_size, void* d_ws, size_t ws_size,
                              hipStream_t stream) {
  (void)in_sizes; (void)n_in; (void)out_size; (void)ws_size;
  const float* env    = (const float*)d_in[0];
  const float* hxs    = (const float*)d_in[1];
  const float* cxs    = (const float*)d_in[2];
  const float* mkeys  = (const float*)d_in[3];
  const float* mvals  = (const float*)d_in[4];
  const float* W_ih   = (const float*)d_in[5];
  const float* W_hh   = (const float*)d_in[6];
  const float* bias   = (const float*)d_in[7];
  const float* ln_g   = (const float*)d_in[8];
  const float* ln_b   = (const float*)d_in[9];
  const float* Wc     = (const float*)d_in[10];
  const float* bc     = (const float*)d_in[11];
  const float* Wa     = (const float*)d_in[12];
  const float* ba     = (const float*)d_in[13];

  float* ws = (float*)d_ws;
  float* c1   = ws + OFF_C1;
  float* q    = ws + OFF_Q;
  __hip_bfloat16* h1b = (__hip_bfloat16*)(ws + OFF_H1B);
  float* pv   = ws + OFF_PV;
  int*   pi   = (int*)(ws + OFF_PI);
  __hip_bfloat16* memB = (__hip_bfloat16*)(ws + OFF_MEMB);  // aliases dead pv/pi
  float* out = (float*)d_out;

  gemm_lstm<1, float, float><<<dim3(HID / 32, BATCH / 64), 512, 0, stream>>>(
      env, hxs, W_ih, W_hh, bias, cxs, c1, h1b, nullptr, nullptr);
  ln_q_np<<<BATCH / 4, 256, 0, stream>>>(c1, ln_g, ln_b, q);
  score_topk<<<dim3(NCHUNK, BATCH / 128), 512, 0, stream>>>(q, mkeys, pv, pi);
  merge_topk<<<BATCH / 4, 256, 0, stream>>>(pv, pi, out + OUT_INDS, out + OUT_W);
  gather_mem<<<BATCH, 256, 0, stream>>>(out + OUT_W, out + OUT_INDS, mvals, memB);
  gemm_lstm<2, __hip_bfloat16, float>
      <<<dim3(HID / 32, BATCH / 64), 512, 0, stream>>>(
      memB, h1b, W_ih, W_hh, bias, c1, nullptr, nullptr,
      out + OUT_H2, out + OUT_C2);
  heads<<<BATCH / 16, 256, 0, stream>>>(out + OUT_H2, Wc, bc, Wa, ba,
                                        out + OUT_CRITIC, out + OUT_ACTOR);
}

// Round 20
// 3753.293 us; speedup vs baseline: 1.3205x; 1.3205x over previous
//
#include <hip/hip_runtime.h>
#include <hip/hip_bf16.h>
#include <math.h>

#define BATCH 4096
#define HID   512
#define NACT  18
#define DIM   1043
#define MEMN  32768
#define TOPK  32
#define G4H   2048
#define NCHUNK 16
#define CHUNKM (MEMN / NCHUNK)   /* 2048 */
#define KCP   512   /* gates-GEMM panel size — DO NOT CHANGE: verified numerics */

// ---- workspace layout (f32-element offsets). PEAK = 9437184 f32 = 36.0 MiB
#define OFF_C1   0ull        // f32 [4096,512]
#define OFF_Q    2097152ull  // f32 [4096,512]
#define OFF_H1B  4194304ull  // bf16 [4096,512]
#define OFF_PV   5242880ull  // f32 [4096,16,32]
#define OFF_PI   7340032ull  // i32 [4096,16,32]
#define OFF_MEMB 5242880ull  // bf16 [4096,1043] ALIASES pv/pi

// ---- output offsets (FLOAT32 elements), return order:
// critic[B,1], actor[B,18], h2[B,512], c2[B,512], inds[B,32], weights[B,32]
#define OUT_CRITIC 0
#define OUT_ACTOR  4096
#define OUT_H2     77824
#define OUT_C2     2174976
#define OUT_INDS   4272128
#define OUT_W      4403200

__device__ __forceinline__ float toF_(float x) { return x; }
__device__ __forceinline__ float toF_(__hip_bfloat16 x) { return __bfloat162float(x); }
__device__ __forceinline__ float sigf_(float x) { return 1.0f / (1.0f + expf(-x)); }

// numpy SIMD f32 exp emulation; sigmoid = 1/(1+exp(-x)) single-rounded.
// tanh: correctly rounded via f64.  DO NOT CHANGE: verified numerics.
__device__ __forceinline__ float np_expf(float x) {
  const float magic = 12582912.0f;  // 0x1.8p23
  float q = fmaf(x, 1.442695040888963f, magic) - magic;  // rint(x*log2e)
  float r = fmaf(q, -6.93145752e-1f, x);
  r = fmaf(q, -1.42860677e-6f, r);
  float num = fmaf(5.082762527590693718096e-04f, r, 6.757896990527504603057e-03f);
  num = fmaf(num, r, 5.114512081637298353406e-02f);
  num = fmaf(num, r, 2.473615434895520810817e-01f);
  num = fmaf(num, r, 7.257664613233124478488e-01f);
  num = fmaf(num, r, 9.999999999980870924916e-01f);
  float den = fmaf(2.159509375685829852307e-02f, r, -2.742335390411667452936e-01f);
  den = fmaf(den, r, 1.0f);
  float poly = __fdiv_rn(num, den);
  int qi = (int)q;
  float scale = __uint_as_float((unsigned)(127 + qi) << 23);
  return __fmul_rn(poly, scale);
}
__device__ __forceinline__ float np_sigmoidf(float x) {
  const float e = np_expf(-x);
  return __fdiv_rn(1.0f, __fadd_rn(1.0f, e));
}
__device__ __forceinline__ float cr_tanhf(float x) { return (float)tanh((double)x); }

// ============================================================================
// Fused GEMM + LSTM cell — VERIFIED NUMERICS (R16/R17 pass). Unchanged.
// ============================================================================
template<int PASS, typename TA, typename TC>
__global__ __launch_bounds__(512, 2) void gemm_lstm(
    const TA* __restrict__ A1, const TA* __restrict__ A2,
    const float* __restrict__ W1, const float* __restrict__ W2,
    const float* __restrict__ bias, const TC* __restrict__ cprev,
    float* __restrict__ c1out, __hip_bfloat16* __restrict__ h1b,
    float* __restrict__ outH2, float* __restrict__ outC2)
{
  __shared__ float as[32][66];
  __shared__ float bs[32][132];
  const int tid = threadIdx.x;
  const int b0 = blockIdx.y * 64;
  const int h0 = blockIdx.x * 32;
  const int tr = tid >> 5, tc = tid & 31;
  float accA[4][4] = {};
  float accB[4][4] = {};

  auto run = [&](const TA* __restrict__ A, const float* __restrict__ W,
                 int Ksz, float (&acc)[4][4]) {
    float accP[4][4] = {};
    for (int k0 = 0; k0 < Ksz; k0 += 32) {
      {
        const int r = tid >> 3, kq = tid & 7;
        #pragma unroll
        for (int j = 0; j < 4; ++j) {
          const int kidx = k0 + 4 * kq + j;
          as[4 * kq + j][r] =
              (kidx < Ksz) ? toF_(A[(size_t)(b0 + r) * Ksz + kidx]) : 0.0f;
        }
      }
      {
        const int kk = tid >> 4, sub = tid & 15;
        const bool ok = (k0 + kk) < Ksz;
        #pragma unroll
        for (int g = 0; g < 4; ++g)
          #pragma unroll
          for (int r2 = 0; r2 < 2; ++r2) {
            const float w =
                ok ? W[(size_t)(k0 + kk) * G4H + 512 * g + h0 + 2 * sub + r2] : 0.0f;
            bs[kk][(2 * sub + r2) * 4 + g] = w;
          }
      }
      __syncthreads();
      #pragma unroll
      for (int kk = 0; kk < 32; ++kk) {
        float a[4], b[4];
        #pragma unroll
        for (int u = 0; u < 4; ++u) a[u] = as[kk][4 * tr + u];
        #pragma unroll
        for (int u = 0; u < 4; ++u) b[u] = bs[kk][4 * tc + u];
        #pragma unroll
        for (int jj = 0; jj < 4; ++jj)
          #pragma unroll
          for (int g = 0; g < 4; ++g)
            accP[jj][g] = fmaf(a[jj], b[g], accP[jj][g]);
      }
      __syncthreads();
      if (((k0 + 32) % KCP == 0) || (k0 + 32 >= Ksz)) {
        #pragma unroll
        for (int jj = 0; jj < 4; ++jj)
          #pragma unroll
          for (int g = 0; g < 4; ++g) {
            acc[jj][g] = __fadd_rn(acc[jj][g], accP[jj][g]);
            accP[jj][g] = 0.0f;
          }
      }
    }
  };
  run(A1, W1, DIM, accA);   // K=1043: panels 512 | 512 | 19
  run(A2, W2, HID, accB);   // K=512: single chain

  const int h = h0 + tc;
  const float bf = bias[h];
  const float bi = bias[512 + h];
  const float bo = bias[1024 + h];
  const float bg = bias[1536 + h];
  #pragma unroll
  for (int jj = 0; jj < 4; ++jj) {
    const int b = b0 + 4 * tr + jj;
    const float fv = __fadd_rn(__fadd_rn(accA[jj][0], accB[jj][0]), bf);
    const float iv = __fadd_rn(__fadd_rn(accA[jj][1], accB[jj][1]), bi);
    const float ov = __fadd_rn(__fadd_rn(accA[jj][2], accB[jj][2]), bo);
    const float gv = __fadd_rn(__fadd_rn(accA[jj][3], accB[jj][3]), bg);
    const float cp = toF_(cprev[(size_t)b * HID + h]);
    if constexpr (PASS == 1) {
      const float sf = np_sigmoidf(fv);
      const float si = np_sigmoidf(iv);
      const float so = np_sigmoidf(ov);
      const float tg = cr_tanhf(gv);
      const float cn = __fadd_rn(__fmul_rn(sf, cp), __fmul_rn(si, tg));
      const float hn = __fmul_rn(so, cr_tanhf(cn));
      c1out[(size_t)b * HID + h] = cn;
      h1b[(size_t)b * HID + h] = __float2bfloat16(hn);
    } else {
      const float cn = sigf_(fv) * cp + sigf_(iv) * tanhf(gv);
      const float hn = sigf_(ov) * tanhf(cn);
      outC2[(size_t)b * HID + h] = cn;
      outH2[(size_t)b * HID + h] = hn;
    }
  }
}

// ============================================================================
// LayerNorm(c1) -> q (numpy pairwise emulation — verified). Unchanged.
// ============================================================================
__global__ __launch_bounds__(256) void ln_q_np(
    const float* __restrict__ c1, const float* __restrict__ ln_g,
    const float* __restrict__ ln_b, float* __restrict__ q)
{
  const int tid = threadIdx.x, lane = tid & 63;
  const int r = blockIdx.x * 4 + (tid >> 6);
  const float* c = c1 + (size_t)r * HID;

  float part;
  {
    const int bi = (lane & 31) >> 3, j = lane & 7;
    const float* p = c + bi * 128 + j;
    float s = p[0];
    #pragma unroll
    for (int k = 1; k < 16; ++k) s = __fadd_rn(s, p[8 * k]);
    part = s;
  }
  part = __fadd_rn(part, __shfl_xor(part, 1, 32));
  part = __fadd_rn(part, __shfl_xor(part, 2, 32));
  part = __fadd_rn(part, __shfl_xor(part, 4, 32));
  part = __fadd_rn(part, __shfl_xor(part, 8, 32));
  part = __fadd_rn(part, __shfl_xor(part, 16, 32));
  const float mean = __fmul_rn(part, 1.0f / 512.0f);

  float part2;
  {
    const int bi = (lane & 31) >> 3, j = lane & 7;
    const float* p = c + bi * 128 + j;
    float d = __fsub_rn(p[0], mean);
    float s = __fmul_rn(d, d);
    #pragma unroll
    for (int k = 1; k < 16; ++k) {
      d = __fsub_rn(p[8 * k], mean);
      s = __fadd_rn(s, __fmul_rn(d, d));
    }
    part2 = s;
  }
  part2 = __fadd_rn(part2, __shfl_xor(part2, 1, 32));
  part2 = __fadd_rn(part2, __shfl_xor(part2, 2, 32));
  part2 = __fadd_rn(part2, __shfl_xor(part2, 4, 32));
  part2 = __fadd_rn(part2, __shfl_xor(part2, 8, 32));
  part2 = __fadd_rn(part2, __shfl_xor(part2, 16, 32));
  const float var = __fmul_rn(part2, 1.0f / 512.0f);

  const float S = __fsqrt_rn(__fadd_rn(var, 1e-5f));
  #pragma unroll
  for (int u = 0; u < 8; ++u) {
    const int i = lane + 64 * u;
    const float dv = __fsub_rn(c[i], mean);
    q[(size_t)r * HID + i] =
        __fadd_rn(__fmul_rn(__fdiv_rn(dv, S), ln_g[i]), ln_b[i]);
  }
}

// ============================================================================
// Fused scores GEMM + exact top-32 — CONSERVATIVE retile: 64x256 tile,
// 4 rows x 8 cols per thread (acc[32], listV[4] — R17 register class, no
// launch-bound cap). Per kk: 3 ds_read_b128 (1 a-broadcast + 2 b at uniform
// 4*cg bank-quads) feed 32 FMA (R17: 2 per 16). Merge = R17's VERIFIED loop
// run twice (cols 0-127, then 128-255 — ascending order preserved).
// NUMERICS: single ascending-K fmaf chain per output — bit-identical.
// ============================================================================
__global__ __launch_bounds__(512) void score_topk(
    const float* __restrict__ Q, const float* __restrict__ Km,
    float* __restrict__ pv, int* __restrict__ pi)
{
  __shared__ float as[32][68];    // [k][row 0..63] (R17 layout)
  __shared__ float bs[32][264];   // [k][col 0..255] (+pad)
  const int tid = threadIdx.x;
  const int lane = tid & 63;
  const int w = tid >> 6;
  const int cg = lane & 31;
  const int hi = lane >> 5;
  const int b0 = blockIdx.y * 64;
  const int chunkBase = blockIdx.x * CHUNKM;
  const int rowbase = 4 * (2 * w + hi);   // 4 rows per thread

  float listV[4];
  int   listI[4];
  #pragma unroll
  for (int j = 0; j < 4; ++j) { listV[j] = -INFINITY; listI[j] = 0; }

  for (int t = 0; t < CHUNKM / 256; ++t) {
    const int m0 = chunkBase + t * 256;
    float acc[4][8] = {};
    for (int k0 = 0; k0 < HID; k0 += 32) {
      {
        // A staging (R17 pattern, 64 rows)
        const int r = tid >> 3, kq = tid & 7;
        const float4 v = *(const float4*)(Q + (size_t)(b0 + r) * HID + k0 + 4 * kq);
        as[4 * kq + 0][r] = v.x; as[4 * kq + 1][r] = v.y;
        as[4 * kq + 2][r] = v.z; as[4 * kq + 3][r] = v.w;
      }
      {
        // B staging: 256 cols, each thread loads one col's 16-k half
        const int bcol = tid >> 1, bkq = tid & 1;
        const float* kp = Km + (size_t)(m0 + bcol) * HID + k0 + 16 * bkq;
        #pragma unroll
        for (int u = 0; u < 4; ++u) {
          const float4 v = *(const float4*)(kp + 4 * u);
          bs[16 * bkq + 4 * u + 0][bcol] = v.x;
          bs[16 * bkq + 4 * u + 1][bcol] = v.y;
          bs[16 * bkq + 4 * u + 2][bcol] = v.z;
          bs[16 * bkq + 4 * u + 3][bcol] = v.w;
        }
      }
      __syncthreads();
      #pragma unroll
      for (int kk = 0; kk < 32; ++kk) {
        const float4 av = *(const float4*)&as[kk][rowbase];
        const float4 bv0 = *(const float4*)&bs[kk][4 * cg];
        const float4 bv1 = *(const float4*)&bs[kk][128 + 4 * cg];
        const float a[4] = {av.x, av.y, av.z, av.w};
        const float b[8] = {bv0.x, bv0.y, bv0.z, bv0.w,
                            bv1.x, bv1.y, bv1.z, bv1.w};
        #pragma unroll
        for (int j = 0; j < 4; ++j)
          #pragma unroll
          for (int c = 0; c < 8; ++c)
            acc[j][c] = fmaf(a[j], b[c], acc[j][c]);
      }
      __syncthreads();
    }
    // ---- merge: two passes of the VERIFIED R17 merge loop
    // pass 0: cols m0 + 4*src'+cc (0..127); pass 1: cols m0+128+...
    #pragma unroll
    for (int half = 0; half < 2; ++half) {
      const int mbase = m0 + 128 * half;
      #pragma unroll
      for (int j = 0; j < 4; ++j) {
        float thr = __shfl(listV[j], hi ? 63 : 31);
        float ca[4];
        #pragma unroll
        for (int cc = 0; cc < 4; ++cc) ca[cc] = acc[j][4 * half + cc];
        while (true) {
          const bool any = (ca[0] > thr) || (ca[1] > thr) ||
                           (ca[2] > thr) || (ca[3] > thr);
          unsigned long long m = __ballot(any);
          if (!m) break;
          const int src = __builtin_ctzll(m);
          const bool participate = (hi == (src >> 5));
          #pragma unroll
          for (int cc = 0; cc < 4; ++cc) {
            const float cv = __shfl(ca[cc], src);
            const float thr_src = __shfl(thr, src);
            if (cv > thr_src) {
              const int ci = mbase + 4 * (src & 31) + cc;
              const unsigned long long em =
                  __ballot(participate && (listV[j] < cv));
              if (em) {
                const int pslot = __builtin_ctzll(em) & 31;
                const float shV = __shfl_up(listV[j], 1);
                const int  shI = __shfl_up(listI[j], 1);
                const int slot = lane & 31;
                if (participate && slot >= pslot) {
                  listV[j] = (slot == pslot) ? cv : shV;
                  listI[j] = (slot == pslot) ? ci : shI;
                }
                thr = __shfl(listV[j], hi ? 63 : 31);
              }
            }
          }
          if (lane == src) { ca[0] = ca[1] = ca[2] = ca[3] = -INFINITY; }
        }
      }
    }
  }
  #pragma unroll
  for (int j = 0; j < 4; ++j) {
    const int row = b0 + rowbase + j;
    const size_t o = ((size_t)row * NCHUNK + blockIdx.x) * TOPK + cg;
    pv[o] = listV[j];
    pi[o] = listI[j];
  }
}

// ============================================================================
// Merge NCHUNK partial top-32s per row -> final sorted top-32 + softmax.
// Unchanged (verified).
// ============================================================================
__global__ __launch_bounds__(256) void merge_topk(
    const float* __restrict__ pv, const int* __restrict__ pi,
    float* __restrict__ outI, float* __restrict__ outW)
{
  const int tid = threadIdx.x;
  const int lane = tid & 63;
  const int b = blockIdx.x * 4 + (tid >> 6);
  float lv = -INFINITY;
  int li = 0;
  const size_t base = (size_t)b * (NCHUNK * TOPK);
  #pragma unroll
  for (int t = 0; t < (NCHUNK * TOPK) / 64; ++t) {
    const float v = pv[base + t * 64 + lane];
    const int ii = pi[base + t * 64 + lane];
    float thr = __shfl(lv, 31);
    unsigned long long m = __ballot(v > thr);
    while (m) {
      const int src = __builtin_ctzll(m);
      m &= (m - 1);
      const float cv = __shfl(v, src);
      const int ci = __shfl(ii, src);
      if (cv > thr) {
        const unsigned long long em = __ballot((lane < 32) && (lv < cv));
        if (em) {
          const int p = __builtin_ctzll(em);
          const float shV = __shfl_up(lv, 1);
          const int shI = __shfl_up(li, 1);
          if ((lane < 32) && lane >= p) {
            lv = (lane == p) ? cv : shV;
            li = (lane == p) ? ci : shI;
          }
          thr = __shfl(lv, 31);
        }
      }
    }
  }
  const float maxv = __shfl(lv, 0);
  float e = (lane < 32) ? expf(lv - maxv) : 0.0f;
  float s = e;
  #pragma unroll
  for (int d = 1; d < 64; d <<= 1) s += __shfl_xor(s, d);
  const float w = e / s;
  if (lane < 32) {
    outI[(size_t)b * TOPK + lane] = (float)li;
    outW[(size_t)b * TOPK + lane] = w;
  }
}

// ============================================================================
// memories[b,:] = sum_s w[s] * mem_values[idx[s], :]  (bf16). Unchanged.
// ============================================================================
__global__ __launch_bounds__(256) void gather_mem(
    const float* __restrict__ wf, const float* __restrict__ inf_,
    const float* __restrict__ mv, __hip_bfloat16* __restrict__ memB)
{
  __shared__ float wl[TOPK];
  __shared__ int il[TOPK];
  const int b = blockIdx.x, tid = threadIdx.x;
  if (tid < TOPK) {
    wl[tid] = wf[(size_t)b * TOPK + tid];
    il[tid] = (int)inf_[(size_t)b * TOPK + tid];
  }
  __syncthreads();
  for (int c = tid; c < DIM; c += 256) {
    float acc = 0.0f;
    #pragma unroll
    for (int s = 0; s < TOPK; ++s)
      acc = fmaf(wl[s], mv[(size_t)il[s] * DIM + c], acc);
    memB[(size_t)b * DIM + c] = __float2bfloat16(acc);
  }
}

// ============================================================================
// critic/actor heads; reads h2 (f32) from d_out, writes f32. Unchanged.
// ============================================================================
__global__ __launch_bounds__(256) void heads(
    const float* __restrict__ h2f,
    const float* __restrict__ Wc, const float* __restrict__ bc,
    const float* __restrict__ Wa, const float* __restrict__ ba,
    float* __restrict__ outC, float* __restrict__ outA)
{
  __shared__ float W[HID * 19];
  const int tid = threadIdx.x, lane = tid & 63, wid = tid >> 6;
  for (int idx = tid; idx < HID * 19; idx += 256) {
    const int l = idx / 19, o = idx % 19;
    W[idx] = (o < NACT) ? Wa[l * NACT + o] : Wc[l];
  }
  __syncthreads();
  const int r0 = blockIdx.x * 16 + wid * 4;
  for (int rr = 0; rr < 4; ++rr) {
    const int r = r0 + rr;
    float hv[8];
    #pragma unroll
    for (int u = 0; u < 8; ++u) hv[u] = h2f[(size_t)r * HID + lane + 64 * u];
    for (int o = 0; o < 19; ++o) {
      float s = 0.f;
      #pragma unroll
      for (int u = 0; u < 8; ++u) s = fmaf(hv[u], W[(lane + 64 * u) * 19 + o], s);
      #pragma unroll
      for (int d = 1; d < 64; d <<= 1) s += __shfl_xor(s, d);
      if (lane == 0) {
        if (o < NACT) outA[(size_t)r * NACT + o] = s + ba[o];
        else          outC[r] = s + bc[0];
      }
    }
  }
}

// ============================================================================
extern "C" void kernel_launch(void* const* d_in, const int* in_sizes, int n_in,
                              void* d_out, int out_size, void* d_ws, size_t ws_size,
                              hipStream_t stream) {
  (void)in_sizes; (void)n_in; (void)out_size; (void)ws_size;
  const float* env    = (const float*)d_in[0];
  const float* hxs    = (const float*)d_in[1];
  const float* cxs    = (const float*)d_in[2];
  const float* mkeys  = (const float*)d_in[3];
  const float* mvals  = (const float*)d_in[4];
  const float* W_ih   = (const float*)d_in[5];
  const float* W_hh   = (const float*)d_in[6];
  const float* bias   = (const float*)d_in[7];
  const float* ln_g   = (const float*)d_in[8];
  const float* ln_b   = (const float*)d_in[9];
  const float* Wc     = (const float*)d_in[10];
  const float* bc     = (const float*)d_in[11];
  const float* Wa     = (const float*)d_in[12];
  const float* ba     = (const float*)d_in[13];

  float* ws = (float*)d_ws;
  float* c1   = ws + OFF_C1;
  float* q    = ws + OFF_Q;
  __hip_bfloat16* h1b = (__hip_bfloat16*)(ws + OFF_H1B);
  float* pv   = ws + OFF_PV;
  int*   pi   = (int*)(ws + OFF_PI);
  __hip_bfloat16* memB = (__hip_bfloat16*)(ws + OFF_MEMB);  // aliases dead pv/pi
  float* out = (float*)d_out;

  gemm_lstm<1, float, float><<<dim3(HID / 32, BATCH / 64), 512, 0, stream>>>(
      env, hxs, W_ih, W_hh, bias, cxs, c1, h1b, nullptr, nullptr);
  ln_q_np<<<BATCH / 4, 256, 0, stream>>>(c1, ln_g, ln_b, q);
  score_topk<<<dim3(NCHUNK, BATCH / 64), 512, 0, stream>>>(q, mkeys, pv, pi);
  merge_topk<<<BATCH / 4, 256, 0, stream>>>(pv, pi, out + OUT_INDS, out + OUT_W);
  gather_mem<<<BATCH, 256, 0, stream>>>(out + OUT_W, out + OUT_INDS, mvals, memB);
  gemm_lstm<2, __hip_bfloat16, float>
      <<<dim3(HID / 32, BATCH / 64), 512, 0, stream>>>(
      memB, h1b, W_ih, W_hh, bias, c1, nullptr, nullptr,
      out + OUT_H2, out + OUT_C2);
  heads<<<BATCH / 16, 256, 0, stream>>>(out + OUT_H2, Wc, bc, Wa, ba,
                                        out + OUT_CRITIC, out + OUT_ACTOR);
}